// Round 5
// baseline (419.128 us; speedup 1.0000x reference)
//
#include <hip/hip_runtime.h>
#include <hip/hip_bf16.h>
#include <cstddef>

#define NN 50000
#define EE 800000
#define TE 850000   // EE + NN self loops
#define INC 256
#define C1 128      // heads(2) * hid(64)
#define C2 64
#define NCHUNK 49   // ceil(NN/1024)

typedef unsigned short ushort_t;
typedef short bf16x8 __attribute__((ext_vector_type(8)));
typedef float f32x4 __attribute__((ext_vector_type(4)));

__device__ inline ushort_t bf16r(float f) {  // RNE float->bf16
    unsigned u = __float_as_uint(f);
    unsigned r = (u + 0x7fffu + ((u >> 16) & 1u)) >> 16;
    return (ushort_t)r;
}
#define BF2F(u) (__uint_as_float(((unsigned)(u)) << 16))
#define LOF(u) (__uint_as_float((u) << 16))           // low bf16 of packed uint
#define HIF(u) (__uint_as_float((u) & 0xffff0000u))   // high bf16 of packed uint

// ---------------- CSR build ----------------

__global__ void k_zero(int* p, int n) {
    int i = blockIdx.x * blockDim.x + threadIdx.x;
    if (i < n) p[i] = 0;
}

__global__ void k_count(const int* __restrict__ ei, int* __restrict__ deg) {
    int e = blockIdx.x * blockDim.x + threadIdx.x;
    if (e >= TE) return;
    int dst = (e < EE) ? ei[EE + e] : (e - EE);
    atomicAdd(&deg[dst], 1);
}

__global__ void k_scan1(const int* __restrict__ deg, int* __restrict__ incl,
                        int* __restrict__ totals) {
    __shared__ int lds[1024];
    int t = threadIdx.x;
    int i = blockIdx.x * 1024 + t;
    int v = (i < NN) ? deg[i] : 0;
    lds[t] = v;
    __syncthreads();
    for (int off = 1; off < 1024; off <<= 1) {
        int add = (t >= off) ? lds[t - off] : 0;
        __syncthreads();
        lds[t] += add;
        __syncthreads();
    }
    if (i < NN) incl[i] = lds[t];
    if (t == 1023) totals[blockIdx.x] = lds[t];
}

__global__ void k_scan2(const int* __restrict__ totals, int* __restrict__ chunkoff) {
    int t = threadIdx.x;
    int orig = (t < NCHUNK) ? totals[t] : 0;
    int v = orig;
    for (int off = 1; off < 64; off <<= 1) {
        int u = __shfl_up(v, off, 64);
        if (t >= off) v += u;
    }
    if (t < NCHUNK) chunkoff[t] = v - orig;
}

__global__ void k_scan3(const int* __restrict__ incl, const int* __restrict__ deg,
                        const int* __restrict__ chunkoff, int* __restrict__ rowstart,
                        int* __restrict__ writeptr) {
    int i = blockIdx.x * blockDim.x + threadIdx.x;
    if (i == 0) rowstart[NN] = TE;
    if (i >= NN) return;
    int rs = incl[i] - deg[i] + chunkoff[i >> 10];
    rowstart[i] = rs;
    writeptr[i] = rs;
}

__global__ void k_scatter(const int* __restrict__ ei, int* __restrict__ writeptr,
                          int2* __restrict__ ssd) {
    int e = blockIdx.x * blockDim.x + threadIdx.x;
    if (e >= TE) return;
    int s, d;
    if (e < EE) { s = ei[e]; d = ei[EE + e]; }
    else        { s = e - EE; d = s; }
    int pos = atomicAdd(&writeptr[d], 1);
    ssd[pos] = make_int2(s, d);
}

// ---------------- casts / weight prep ----------------

__global__ void k_cast4(const float* __restrict__ src, ushort_t* __restrict__ dst, int n4) {
    int i = blockIdx.x * blockDim.x + threadIdx.x;
    if (i >= n4) return;
    float4 a = ((const float4*)src)[i];
    ushort4 o;
    o.x = bf16r(a.x); o.y = bf16r(a.y); o.z = bf16r(a.z); o.w = bf16r(a.w);
    ((ushort4*)dst)[i] = o;
}

__global__ void k_prep_w(const float* __restrict__ Wl, const float* __restrict__ Wr,
                         const float* __restrict__ bl, const float* __restrict__ br,
                         ushort_t* __restrict__ Wt, float* __restrict__ biasf,
                         int K, int HALF) {
    int n = blockIdx.x;
    int k = threadIdx.x;
    const float* W = (n < HALF) ? Wl : Wr;
    int c = (n < HALF) ? n : n - HALF;
    Wt[(size_t)n * K + k] = bf16r(W[(size_t)k * HALF + c]);
    if (n == 0 && k < 2 * HALF) biasf[k] = (k < HALF) ? bl[k] : br[k - HALF];
}

// ---------------- bf16 MFMA GEMM ----------------
// C[M,NCOL](bf16) = A[M,K](bf16) @ Bt[NCOL,K]^T + bias(fp32)
// 128x128 tile, BK=32, 256 threads, 16x16x32 MFMA; LDS rows padded to 40 bf16.

template <int K, int NCOL>
__global__ __launch_bounds__(256) void k_gemm_mfma(const ushort_t* __restrict__ A,
                                                   const ushort_t* __restrict__ Bt,
                                                   const float* __restrict__ bias,
                                                   ushort_t* __restrict__ C, int M) {
    __shared__ __align__(16) ushort_t As[128 * 40];
    __shared__ __align__(16) ushort_t Bs[128 * 40];
    int tid = threadIdx.x;
    int bm = blockIdx.x * 128;
    int bn = blockIdx.y * 128;
    int w = tid >> 6, l = tid & 63;
    int wm = (w & 1) * 64, wn = (w >> 1) * 64;
    int lm = l & 15, half = l >> 4;

    f32x4 zero = {0.f, 0.f, 0.f, 0.f};
    f32x4 acc[4][4];
#pragma unroll
    for (int a = 0; a < 4; a++)
#pragma unroll
        for (int b = 0; b < 4; b++) acc[a][b] = zero;

    for (int k0 = 0; k0 < K; k0 += 32) {
#pragma unroll
        for (int q = 0; q < 2; q++) {
            int seg = q * 256 + tid;
            int m = seg >> 2;
            int ko = (seg & 3) * 8;
            *(float4*)&As[m * 40 + ko] = *(const float4*)&A[(size_t)(bm + m) * K + k0 + ko];
            *(float4*)&Bs[m * 40 + ko] = *(const float4*)&Bt[(size_t)(bn + m) * K + k0 + ko];
        }
        __syncthreads();
        bf16x8 af[4], bfr[4];
#pragma unroll
        for (int mi = 0; mi < 4; mi++)
            af[mi] = *(const bf16x8*)&As[(wm + mi * 16 + lm) * 40 + half * 8];
#pragma unroll
        for (int ni = 0; ni < 4; ni++)
            bfr[ni] = *(const bf16x8*)&Bs[(wn + ni * 16 + lm) * 40 + half * 8];
#pragma unroll
        for (int mi = 0; mi < 4; mi++)
#pragma unroll
            for (int ni = 0; ni < 4; ni++)
                acc[mi][ni] = __builtin_amdgcn_mfma_f32_16x16x32_bf16(
                    af[mi], bfr[ni], acc[mi][ni], 0, 0, 0);
        __syncthreads();
    }
#pragma unroll
    for (int ni = 0; ni < 4; ni++) {
        int col = bn + wn + ni * 16 + lm;
        float bv = bias[col];
#pragma unroll
        for (int mi = 0; mi < 4; mi++) {
            int rbase = bm + wm + mi * 16 + half * 4;
#pragma unroll
            for (int r = 0; r < 4; r++) {
                int row = rbase + r;
                if (row < M) C[(size_t)row * NCOL + col] = bf16r(acc[mi][ni][r] + bv);
            }
        }
    }
}

// ---------------- Pass A: edge-parallel logits ----------------
// 4 lanes per edge; lane q covers chunk c = q + 4*it (8 channels each).

__device__ inline float lrelu_dot2(unsigned ua, unsigned ub, float at_lo, float at_hi) {
    float alo = __uint_as_float(ua << 16), ahi = __uint_as_float(ua & 0xffff0000u);
    float blo = __uint_as_float(ub << 16), bhi = __uint_as_float(ub & 0xffff0000u);
    float t0 = alo + blo, t1 = ahi + bhi;
    float l0 = fmaxf(t0, 0.f) + 0.2f * fminf(t0, 0.f);
    float l1 = fmaxf(t1, 0.f) + 0.2f * fminf(t1, 0.f);
    return at_lo * l0 + at_hi * l1;
}

template <int STRIDE, int ITS, int HEADS>
__global__ __launch_bounds__(256) void k_edge(
    const ushort_t* __restrict__ xlr,
    const int2* __restrict__ ssd,
    const float* __restrict__ att, float* __restrict__ p) {
    int l = threadIdx.x & 63;
    int wv = threadIdx.x >> 6;
    int q = l & 3;
    int j = blockIdx.x * 64 + wv * 16 + (l >> 2);
    if (j >= TE) return;
    int2 sd = ssd[j];
    const ushort_t* xl = xlr + (size_t)sd.x * STRIDE;
    const ushort_t* xr = xlr + (size_t)sd.y * STRIDE + STRIDE / 2;
    float w[HEADS];
#pragma unroll
    for (int h = 0; h < HEADS; h++) w[h] = 0.f;
#pragma unroll
    for (int it = 0; it < ITS; it++) {
        int c = q + 4 * it;  // chunk of 8 channels
        uint4 a = *(const uint4*)&xl[c * 8];
        uint4 b = *(const uint4*)&xr[c * 8];
        float4 t0 = *(const float4*)&att[c * 8];
        float4 t1 = *(const float4*)&att[c * 8 + 4];
        int h = (HEADS == 2 && it >= ITS / 2) ? 1 : 0;
        float d = lrelu_dot2(a.x, b.x, t0.x, t0.y)
                + lrelu_dot2(a.y, b.y, t0.z, t0.w)
                + lrelu_dot2(a.z, b.z, t1.x, t1.y)
                + lrelu_dot2(a.w, b.w, t1.z, t1.w);
        w[h] += d;
    }
#pragma unroll
    for (int h = 0; h < HEADS; h++) {
        w[h] += __shfl_xor(w[h], 1, 64);
        w[h] += __shfl_xor(w[h], 2, 64);
    }
    if (q == 0) {
        if (HEADS == 2)
            ((float2*)p)[j] = make_float2(__expf(w[0]), __expf(w[1]));
        else
            p[j] = __expf(w[0]);
    }
}

// ---------------- Pass B: node-parallel aggregation + epilogue ----------------
// Lane loads a packed uint = 2 bf16 channels: one 256B wave-instr per edge row.

// Layer 1: block 128 = 2 waves, one node; wave w owns edges {row+w, row+w+2, ...}.
// Lane covers channels {2*lane, 2*lane+1}; head = lane>>5.
__global__ __launch_bounds__(128) void k_aggr1(
    const ushort_t* __restrict__ xlr, const float* __restrict__ p,
    const int* __restrict__ rowstart, const int2* __restrict__ ssd,
    const float* __restrict__ bias,
    const float* __restrict__ g, const float* __restrict__ b,
    const float* __restrict__ m, const float* __restrict__ v,
    ushort_t* __restrict__ out) {
    __shared__ float comb[3][64];
    int i = blockIdx.x;
    int lane = threadIdx.x & 63;
    int wv = threadIdx.x >> 6;
    int head = lane >> 5;
    int row = rowstart[i], end = rowstart[i + 1];
    float ax = 0.f, ay = 0.f, s = 0.f;
    int j = row + wv;
    for (; j + 6 < end; j += 8) {  // 4 edges per wave per iter (stride 2)
        int s0 = ssd[j].x, s1 = ssd[j + 2].x, s2 = ssd[j + 4].x, s3 = ssd[j + 6].x;
        float2 q0 = ((const float2*)p)[j],     q1 = ((const float2*)p)[j + 2];
        float2 q2 = ((const float2*)p)[j + 4], q3 = ((const float2*)p)[j + 6];
        float p0 = head ? q0.y : q0.x, p1 = head ? q1.y : q1.x;
        float p2 = head ? q2.y : q2.x, p3 = head ? q3.y : q3.x;
        unsigned u0 = *(const unsigned*)&xlr[(size_t)s0 * 256 + 2 * lane];
        unsigned u1 = *(const unsigned*)&xlr[(size_t)s1 * 256 + 2 * lane];
        unsigned u2 = *(const unsigned*)&xlr[(size_t)s2 * 256 + 2 * lane];
        unsigned u3 = *(const unsigned*)&xlr[(size_t)s3 * 256 + 2 * lane];
        ax += p0 * LOF(u0) + p1 * LOF(u1) + p2 * LOF(u2) + p3 * LOF(u3);
        ay += p0 * HIF(u0) + p1 * HIF(u1) + p2 * HIF(u2) + p3 * HIF(u3);
        s += (p0 + p1) + (p2 + p3);
    }
    for (; j < end; j += 2) {
        int src = ssd[j].x;
        float2 q = ((const float2*)p)[j];
        float pj = head ? q.y : q.x;
        unsigned u = *(const unsigned*)&xlr[(size_t)src * 256 + 2 * lane];
        ax += pj * LOF(u);
        ay += pj * HIF(u);
        s += pj;
    }
    if (wv == 1) { comb[0][lane] = ax; comb[1][lane] = ay; comb[2][lane] = s; }
    __syncthreads();
    if (wv == 0) {
        ax += comb[0][lane]; ay += comb[1][lane]; s += comb[2][lane];
        float inv = 1.f / s;
        float2 bb = ((const float2*)bias)[lane];
        float2 mm = ((const float2*)m)[lane];
        float2 vv = ((const float2*)v)[lane];
        float2 gg = ((const float2*)g)[lane];
        float2 bb2 = ((const float2*)b)[lane];
        float ox = ax * inv + bb.x, oy = ay * inv + bb.y;
        ox = (ox - mm.x) * rsqrtf(vv.x + 1e-5f) * gg.x + bb2.x;
        oy = (oy - mm.y) * rsqrtf(vv.y + 1e-5f) * gg.y + bb2.y;
        ox = (ox > 0.f) ? ox : (__expf(ox) - 1.f);
        oy = (oy > 0.f) ? oy : (__expf(oy) - 1.f);
        unsigned wpack = (unsigned)bf16r(ox) | ((unsigned)bf16r(oy) << 16);
        *(unsigned*)&out[(size_t)i * C1 + 2 * lane] = wpack;
    }
}

// Layer 2 + classifier: block 128 = 2 waves, one node; 4 edge slots (wave x half-wave).
// c2 = lane&31 covers channels {2*c2, 2*c2+1}.
__global__ __launch_bounds__(128) void k_aggr2(
    const ushort_t* __restrict__ xlr, const float* __restrict__ p,
    const int* __restrict__ rowstart, const int2* __restrict__ ssd,
    const float* __restrict__ bias,
    const float* __restrict__ g, const float* __restrict__ b,
    const float* __restrict__ m, const float* __restrict__ v,
    const float* __restrict__ Wc, const float* __restrict__ bc,
    float* __restrict__ out) {
    __shared__ float comb[3][32];
    int i = blockIdx.x;
    int lane = threadIdx.x & 63;
    int wv = threadIdx.x >> 6;
    int half = lane >> 5;
    int c2 = lane & 31;
    int row = rowstart[i], end = rowstart[i + 1];
    float ax = 0.f, ay = 0.f, s = 0.f;
    int j = row + wv * 2 + half;
    for (; j + 4 < end; j += 8) {  // 2 edges per slot per iter (stride 4)
        int s0 = ssd[j].x, s1 = ssd[j + 4].x;
        float p0 = p[j], p1 = p[j + 4];
        unsigned u0 = *(const unsigned*)&xlr[(size_t)s0 * 128 + 2 * c2];
        unsigned u1 = *(const unsigned*)&xlr[(size_t)s1 * 128 + 2 * c2];
        ax += p0 * LOF(u0) + p1 * LOF(u1);
        ay += p0 * HIF(u0) + p1 * HIF(u1);
        s += p0 + p1;
    }
    for (; j < end; j += 4) {
        int src = ssd[j].x;
        float pj = p[j];
        unsigned u = *(const unsigned*)&xlr[(size_t)src * 128 + 2 * c2];
        ax += pj * LOF(u);
        ay += pj * HIF(u);
        s += pj;
    }
    ax += __shfl_xor(ax, 32, 64);
    ay += __shfl_xor(ay, 32, 64);
    s  += __shfl_xor(s, 32, 64);
    if (wv == 1 && half == 0) { comb[0][c2] = ax; comb[1][c2] = ay; comb[2][c2] = s; }
    __syncthreads();
    if (wv == 0 && half == 0) {
        ax += comb[0][c2]; ay += comb[1][c2]; s += comb[2][c2];
        float inv = 1.f / s;
        float2 bb = ((const float2*)bias)[c2];
        float2 mm = ((const float2*)m)[c2];
        float2 vv = ((const float2*)v)[c2];
        float2 gg = ((const float2*)g)[c2];
        float2 bb2 = ((const float2*)b)[c2];
        float ox = ax * inv + bb.x, oy = ay * inv + bb.y;
        ox = (ox - mm.x) * rsqrtf(vv.x + 1e-5f) * gg.x + bb2.x;
        oy = (oy - mm.y) * rsqrtf(vv.y + 1e-5f) * gg.y + bb2.y;
        ox = (ox > 0.f) ? ox : (__expf(ox) - 1.f);
        oy = (oy > 0.f) ? oy : (__expf(oy) - 1.f);
        float2 wc = ((const float2*)Wc)[c2];
        float z = ox * wc.x + oy * wc.y;
        z += __shfl_xor(z, 16, 64);
        z += __shfl_xor(z, 8, 64);
        z += __shfl_xor(z, 4, 64);
        z += __shfl_xor(z, 2, 64);
        z += __shfl_xor(z, 1, 64);
        if (lane == 0) out[i] = 1.f / (1.f + __expf(-(z + bc[0])));
    }
}

// ---------------- launch ----------------

extern "C" void kernel_launch(void* const* d_in, const int* in_sizes, int n_in,
                              void* d_out, int out_size, void* d_ws, size_t ws_size,
                              hipStream_t stream) {
    const float* x    = (const float*)d_in[0];
    const int*   ei   = (const int*)d_in[1];
    const float* W1l  = (const float*)d_in[2];
    const float* b1l  = (const float*)d_in[3];
    const float* W1r  = (const float*)d_in[4];
    const float* b1r  = (const float*)d_in[5];
    const float* att1 = (const float*)d_in[6];
    const float* bias1= (const float*)d_in[7];
    const float* bn1g = (const float*)d_in[8];
    const float* bn1b = (const float*)d_in[9];
    const float* bn1m = (const float*)d_in[10];
    const float* bn1v = (const float*)d_in[11];
    const float* W2l  = (const float*)d_in[12];
    const float* b2l  = (const float*)d_in[13];
    const float* W2r  = (const float*)d_in[14];
    const float* b2r  = (const float*)d_in[15];
    const float* att2 = (const float*)d_in[16];
    const float* bias2= (const float*)d_in[17];
    const float* bn2g = (const float*)d_in[18];
    const float* bn2b = (const float*)d_in[19];
    const float* bn2m = (const float*)d_in[20];
    const float* bn2v = (const float*)d_in[21];
    const float* Wc   = (const float*)d_in[22];
    const float* bc   = (const float*)d_in[23];
    float* out = (float*)d_out;

    char* ws = (char*)d_ws;
    size_t off = 0;
    auto alloc = [&](size_t bytes) {
        size_t o = off;
        off += (bytes + 255) & ~(size_t)255;
        return o;
    };
    ushort_t* xb    = (ushort_t*)(ws + alloc((size_t)(NN + 128) * 256 * 2));
    ushort_t* xlr1  = (ushort_t*)(ws + alloc((size_t)NN * 256 * 2));  // reused as xlr2
    ushort_t* h1b   = (ushort_t*)(ws + alloc((size_t)(NN + 128) * 128 * 2));
    ushort_t* Wt1   = (ushort_t*)(ws + alloc((size_t)256 * 256 * 2));
    float*    biasf1= (float*)(ws + alloc(256 * 4));
    ushort_t* Wt2   = (ushort_t*)(ws + alloc((size_t)128 * 128 * 2));
    float*    biasf2= (float*)(ws + alloc(128 * 4));
    int* deg      = (int*)(ws + alloc((size_t)NN * 4));
    int* incl     = (int*)(ws + alloc((size_t)NN * 4));
    int* rowstart = (int*)(ws + alloc((size_t)(NN + 1) * 4));
    int* writeptr = (int*)(ws + alloc((size_t)NN * 4));
    int* totals   = (int*)(ws + alloc(64 * 4));
    int* chunkoff = (int*)(ws + alloc(64 * 4));
    int2* ssd     = (int2*)(ws + alloc((size_t)TE * 8));
    float* pp     = (float*)(ws + alloc((size_t)2 * TE * 4));  // layer1 float2; layer2 float
    ushort_t* xlr2 = xlr1;

    // CSR build
    k_zero<<<(NN + 255) / 256, 256, 0, stream>>>(deg, NN);
    k_count<<<(TE + 255) / 256, 256, 0, stream>>>(ei, deg);
    k_scan1<<<NCHUNK, 1024, 0, stream>>>(deg, incl, totals);
    k_scan2<<<1, 64, 0, stream>>>(totals, chunkoff);
    k_scan3<<<(NN + 255) / 256, 256, 0, stream>>>(incl, deg, chunkoff, rowstart, writeptr);
    k_scatter<<<(TE + 255) / 256, 256, 0, stream>>>(ei, writeptr, ssd);

    // bf16 prep
    int n4x = NN * INC / 4;
    k_cast4<<<(n4x + 255) / 256, 256, 0, stream>>>(x, xb, n4x);
    k_prep_w<<<256, 256, 0, stream>>>(W1l, W1r, b1l, b1r, Wt1, biasf1, 256, 128);
    k_prep_w<<<128, 128, 0, stream>>>(W2l, W2r, b2l, b2r, Wt2, biasf2, 128, 64);

    int eb = (TE + 63) / 64;

    // layer 1
    dim3 gg1((NN + 127) / 128, 2);
    k_gemm_mfma<256, 256><<<gg1, 256, 0, stream>>>(xb, Wt1, biasf1, xlr1, NN);
    k_edge<256, 4, 2><<<eb, 256, 0, stream>>>(xlr1, ssd, att1, pp);
    k_aggr1<<<NN, 128, 0, stream>>>(xlr1, pp, rowstart, ssd, bias1,
                                    bn1g, bn1b, bn1m, bn1v, h1b);

    // layer 2 (+classifier)
    dim3 gg2((NN + 127) / 128, 1);
    k_gemm_mfma<128, 128><<<gg2, 256, 0, stream>>>(h1b, Wt2, biasf2, xlr2, NN);
    k_edge<128, 2, 1><<<eb, 256, 0, stream>>>(xlr2, ssd, att2, pp);
    k_aggr2<<<NN, 128, 0, stream>>>(xlr2, pp, rowstart, ssd, bias2,
                                    bn2g, bn2b, bn2m, bn2v, Wc, bc, out);
}